// Round 1
// baseline (150.593 us; speedup 1.0000x reference)
//
#include <hip/hip_runtime.h>
#include <math.h>

// Problem constants (match reference)
#define B_ 131072
#define T_ 8
#define C_ 32
#define H_ 4
#define D_ 8

// One thread per (b, t) row. The 8 rows of one batch live in an aligned
// 8-lane group of a single wave64, so cross-row k/v exchange for the tiny
// causal attention is done with __shfl. Weights are read with loop-uniform
// indices only -> compiler should emit scalar (s_load) accesses.
__global__ __launch_bounds__(256) void attn_block_kernel(
    const float* __restrict__ X,
    const float* __restrict__ Wq,
    const float* __restrict__ Wk,
    const float* __restrict__ Wv,
    const float* __restrict__ Wf,
    const float* __restrict__ bf,
    float* __restrict__ Y)
{
    const int gid  = blockIdx.x * blockDim.x + threadIdx.x; // row id = b*T + t
    const int t    = gid & 7;
    const int lane = threadIdx.x & 63;
    const int base = lane & 56;   // first lane of this batch's 8-lane group

    // ---- load x row (32 floats) as 8x float4 ----
    float x[C_];
    {
        const float4* xr = reinterpret_cast<const float4*>(X + (size_t)gid * C_);
        #pragma unroll
        for (int i = 0; i < 8; ++i) {
            float4 v4 = xr[i];
            x[i*4+0] = v4.x; x[i*4+1] = v4.y; x[i*4+2] = v4.z; x[i*4+3] = v4.w;
        }
    }

    // ---- FF accumulator, initialized with bias ----
    float y[C_];
    #pragma unroll
    for (int j = 0; j < C_; ++j) y[j] = bf[j];

    const float scale = 0.35355339059327373f; // 1/sqrt(D)

    #pragma unroll 1   // keep h-loop rolled: small I-cache footprint
    for (int h = 0; h < H_; ++h) {
        const float* wq = Wq + h * (C_ * D_);
        const float* wk = Wk + h * (C_ * D_);
        const float* wv = Wv + h * (C_ * D_);

        // ---- projections for this head: q,k,v (D=8 each) ----
        float q[D_], k[D_], v[D_];
        #pragma unroll
        for (int d = 0; d < D_; ++d) { q[d] = 0.f; k[d] = 0.f; v[d] = 0.f; }

        #pragma unroll
        for (int c = 0; c < C_; ++c) {
            const float xc = x[c];
            #pragma unroll
            for (int d = 0; d < D_; ++d) {
                q[d] = fmaf(xc, wq[c*D_ + d], q[d]);
                k[d] = fmaf(xc, wk[c*D_ + d], k[d]);
                v[d] = fmaf(xc, wv[c*D_ + d], v[d]);
            }
        }
        #pragma unroll
        for (int d = 0; d < D_; ++d) q[d] *= scale;

        // ---- scores: q . k_s over the 8-lane batch group, causal mask ----
        float sc[T_];
        #pragma unroll
        for (int s = 0; s < T_; ++s) {
            float dot = 0.f;
            #pragma unroll
            for (int d = 0; d < D_; ++d) {
                float ks = __shfl(k[d], base + s, 64);
                dot = fmaf(q[d], ks, dot);
            }
            sc[s] = (s <= t) ? dot : -1.0e30f;
        }

        // ---- softmax over s (row is thread-local) ----
        float m = sc[0];
        #pragma unroll
        for (int s = 1; s < T_; ++s) m = fmaxf(m, sc[s]);
        float e[T_];
        float sum = 0.f;
        #pragma unroll
        for (int s = 0; s < T_; ++s) { e[s] = __expf(sc[s] - m); sum += e[s]; }
        const float winv = 1.0f / sum;

        // ---- PV: o[d] = sum_s wei[s] * v_s[d] (normalize at the end) ----
        float o[D_];
        #pragma unroll
        for (int d = 0; d < D_; ++d) o[d] = 0.f;
        #pragma unroll
        for (int s = 0; s < T_; ++s) {
            const float w = e[s];
            #pragma unroll
            for (int d = 0; d < D_; ++d) {
                float vs = __shfl(v[d], base + s, 64);
                o[d] = fmaf(w, vs, o[d]);
            }
        }

        // ---- FF accumulate: y += (o*winv) @ Wf[h*8+d, :] ----
        #pragma unroll
        for (int d = 0; d < D_; ++d) {
            const float od = o[d] * winv;
            const float* wf = Wf + (h*D_ + d) * C_;
            #pragma unroll
            for (int j = 0; j < C_; ++j)
                y[j] = fmaf(od, wf[j], y[j]);
        }
    }

    // ---- ReLU + store as 8x float4 ----
    float4* yr = reinterpret_cast<float4*>(Y + (size_t)gid * C_);
    #pragma unroll
    for (int i = 0; i < 8; ++i) {
        float4 v4;
        v4.x = fmaxf(y[i*4+0], 0.f);
        v4.y = fmaxf(y[i*4+1], 0.f);
        v4.z = fmaxf(y[i*4+2], 0.f);
        v4.w = fmaxf(y[i*4+3], 0.f);
        yr[i] = v4;
    }
}

extern "C" void kernel_launch(void* const* d_in, const int* in_sizes, int n_in,
                              void* d_out, int out_size, void* d_ws, size_t ws_size,
                              hipStream_t stream)
{
    const float* X  = (const float*)d_in[0];
    const float* Wq = (const float*)d_in[1];
    const float* Wk = (const float*)d_in[2];
    const float* Wv = (const float*)d_in[3];
    const float* Wf = (const float*)d_in[4];
    const float* bf = (const float*)d_in[5];
    float* Y = (float*)d_out;

    const int rows = B_ * T_;            // 1,048,576
    dim3 grid(rows / 256), block(256);
    hipLaunchKernelGGL(attn_block_kernel, grid, block, 0, stream,
                       X, Wq, Wk, Wv, Wf, bf, Y);
}

// Round 2
// 78.109 us; speedup vs baseline: 1.9280x; 1.9280x over previous
//
#include <hip/hip_runtime.h>
#include <stdint.h>

// Problem constants
#define B_ 131072
#define T_ 8
#define C_ 32
#define H_ 4
#define D_ 8

typedef __attribute__((ext_vector_type(8))) short bf16x8;   // 8 bf16 (4 VGPRs)
typedef __attribute__((ext_vector_type(4))) float f32x4;

union FragU { bf16x8 v; uint32_t u[4]; };

// packed fp32->bf16 (RTNE), 2 values per instruction
__device__ inline uint32_t cvt_pk_bf16(float lo, float hi) {
    uint32_t r;
    asm("v_cvt_pk_bf16_f32 %0, %1, %2" : "=v"(r) : "v"(lo), "v"(hi));
    return r;
}

#define QKV_STRIDE 100   // 96 cols + pad; 100*4 % 32 = 16 -> 2-way banks (free)
#define OUT_STRIDE 36    // 32 cols + pad; avoids the 128B-row 16-way conflict
#define TILES_PER_WAVE 4

// One wave handles 16 rows (= 2 causal batches of T=8) per tile iteration.
// LDS is wave-private: no __syncthreads needed anywhere.
__global__ __launch_bounds__(256, 4) void attn_block_mfma(
    const float* __restrict__ X,
    const float* __restrict__ Wq,
    const float* __restrict__ Wk,
    const float* __restrict__ Wv,
    const float* __restrict__ Wf,
    const float* __restrict__ bfb,
    float* __restrict__ Y)
{
    __shared__ float lds[4][QKV_STRIDE * 16 + OUT_STRIDE * 16];
    const int wid  = threadIdx.x >> 6;
    const int lane = threadIdx.x & 63;
    const int cc = lane & 15;   // col-in-tile / A-row
    const int gg = lane >> 4;   // k-group
    float* qkv  = &lds[wid][0];
    float* outb = &lds[wid][QKV_STRIDE * 16];

    const float scale = 0.35355339059327373f;  // 1/sqrt(D), folded into Wq

    // ---------- preamble: weight B-fragments (held in VGPRs) ----------
    // B-frag layout for mfma_f32_16x16x32_bf16: col = lane&15, k = (lane>>4)*8 + jj
    FragU bW[6];   // tiles 0,1 = q(heads0-1,2-3); 2,3 = k; 4,5 = v
    {
        const float* const Ws[3] = { Wq, Wk, Wv };
        #pragma unroll
        for (int tau = 0; tau < 6; ++tau) {
            const float* Wm = Ws[tau >> 1];
            const int col = (tau & 1) * 16 + cc;
            const int head = col >> 3, d = col & 7;
            float f[8];
            #pragma unroll
            for (int jj = 0; jj < 8; ++jj)
                f[jj] = Wm[head * 256 + (gg * 8 + jj) * 8 + d];
            if (tau < 2) {
                #pragma unroll
                for (int jj = 0; jj < 8; ++jj) f[jj] *= scale;
            }
            bW[tau].u[0] = cvt_pk_bf16(f[0], f[1]);
            bW[tau].u[1] = cvt_pk_bf16(f[2], f[3]);
            bW[tau].u[2] = cvt_pk_bf16(f[4], f[5]);
            bW[tau].u[3] = cvt_pk_bf16(f[6], f[7]);
        }
    }
    FragU bF[2];   // FF weight, output tiles 0,1
    {
        #pragma unroll
        for (int tau = 0; tau < 2; ++tau) {
            const int col = tau * 16 + cc;
            float f[8];
            #pragma unroll
            for (int jj = 0; jj < 8; ++jj)
                f[jj] = Wf[(gg * 8 + jj) * 32 + col];
            bF[tau].u[0] = cvt_pk_bf16(f[0], f[1]);
            bF[tau].u[1] = cvt_pk_bf16(f[2], f[3]);
            bF[tau].u[2] = cvt_pk_bf16(f[4], f[5]);
            bF[tau].u[3] = cvt_pk_bf16(f[6], f[7]);
        }
    }
    // bias for the final row-major store: cols c0..c0+3 and c0+16..c0+19
    const int c0 = (lane & 3) * 4;
    const float4 bias0 = *(const float4*)(bfb + c0);
    const float4 bias1 = *(const float4*)(bfb + c0 + 16);

    const int waveGlobal = blockIdx.x * 4 + wid;
    const f32x4 z = { 0.f, 0.f, 0.f, 0.f };

    // prefetch first X fragment
    int rowbase = waveGlobal * (16 * TILES_PER_WAVE);
    const float* xp = X + (size_t)(rowbase + cc) * 32 + gg * 8;
    float4 xa = *(const float4*)xp;
    float4 xb = *(const float4*)(xp + 4);

    #pragma unroll 1
    for (int it = 0; it < TILES_PER_WAVE; ++it) {
        rowbase = waveGlobal * (16 * TILES_PER_WAVE) + it * 16;

        // ---- A-frag from X (row = lane&15, k = (lane>>4)*8 + j) ----
        FragU aX;
        aX.u[0] = cvt_pk_bf16(xa.x, xa.y);
        aX.u[1] = cvt_pk_bf16(xa.z, xa.w);
        aX.u[2] = cvt_pk_bf16(xb.x, xb.y);
        aX.u[3] = cvt_pk_bf16(xb.z, xb.w);

        // prefetch next tile's X (clamped addr; hides HBM latency under attention)
        {
            const int itn = (it + 1 < TILES_PER_WAVE) ? it + 1 : it;
            const float* xpn = X + (size_t)(waveGlobal * (16 * TILES_PER_WAVE) + itn * 16 + cc) * 32 + gg * 8;
            xa = *(const float4*)xpn;
            xb = *(const float4*)(xpn + 4);
        }

        // ---- QKV projection: 6 MFMAs -> 16 rows x 96 cols ----
        f32x4 cq[6];
        #pragma unroll
        for (int tau = 0; tau < 6; ++tau)
            cq[tau] = __builtin_amdgcn_mfma_f32_16x16x32_bf16(aX.v, bW[tau].v, z, 0, 0, 0);

        // scatter C-frags to LDS: row = gg*4 + r, col = tau*16 + cc
        #pragma unroll
        for (int tau = 0; tau < 6; ++tau) {
            #pragma unroll
            for (int r = 0; r < 4; ++r)
                qkv[(gg * 4 + r) * QKV_STRIDE + tau * 16 + cc] = cq[tau][r];
        }

        // ---- attention: lane = head*16 + row; all 64 lanes busy ----
        const int head = gg;        // 0..3
        const int arow = cc;        // 0..15 (2 batches of 8)
        const int tpos = arow & 7, bb = arow >> 3;

        const float* qr = qkv + arow * QKV_STRIDE + head * 8;
        const float4 qa = *(const float4*)qr;
        const float4 qb = *(const float4*)(qr + 4);

        float sc[8];
        #pragma unroll
        for (int s = 0; s < 8; ++s) {
            const float* kr = qkv + (bb * 8 + s) * QKV_STRIDE + 32 + head * 8;
            const float4 ka = *(const float4*)kr;
            const float4 kb = *(const float4*)(kr + 4);
            float dot =          qa.x * ka.x;
            dot = fmaf(qa.y, ka.y, dot);
            dot = fmaf(qa.z, ka.z, dot);
            dot = fmaf(qa.w, ka.w, dot);
            dot = fmaf(qb.x, kb.x, dot);
            dot = fmaf(qb.y, kb.y, dot);
            dot = fmaf(qb.z, kb.z, dot);
            dot = fmaf(qb.w, kb.w, dot);
            sc[s] = (s <= tpos) ? dot : -1.0e30f;
        }
        float m = sc[0];
        #pragma unroll
        for (int s = 1; s < 8; ++s) m = fmaxf(m, sc[s]);
        float e[8], sum = 0.f;
        #pragma unroll
        for (int s = 0; s < 8; ++s) { e[s] = __expf(sc[s] - m); sum += e[s]; }
        const float winv = 1.0f / sum;

        float4 o03 = { 0.f, 0.f, 0.f, 0.f }, o47 = { 0.f, 0.f, 0.f, 0.f };
        #pragma unroll
        for (int s = 0; s < 8; ++s) {
            const float* vr = qkv + (bb * 8 + s) * QKV_STRIDE + 64 + head * 8;
            const float4 va = *(const float4*)vr;
            const float4 vb = *(const float4*)(vr + 4);
            o03.x = fmaf(e[s], va.x, o03.x);
            o03.y = fmaf(e[s], va.y, o03.y);
            o03.z = fmaf(e[s], va.z, o03.z);
            o03.w = fmaf(e[s], va.w, o03.w);
            o47.x = fmaf(e[s], vb.x, o47.x);
            o47.y = fmaf(e[s], vb.y, o47.y);
            o47.z = fmaf(e[s], vb.z, o47.z);
            o47.w = fmaf(e[s], vb.w, o47.w);
        }
        float4 w0, w1;
        w0.x = o03.x * winv; w0.y = o03.y * winv; w0.z = o03.z * winv; w0.w = o03.w * winv;
        w1.x = o47.x * winv; w1.y = o47.y * winv; w1.z = o47.z * winv; w1.w = o47.w * winv;
        *(float4*)(outb + arow * OUT_STRIDE + head * 8)     = w0;
        *(float4*)(outb + arow * OUT_STRIDE + head * 8 + 4) = w1;

        // ---- FF: A-frag from out (row = cc, k = gg*8 + j) ----
        const float* ar = outb + cc * OUT_STRIDE + gg * 8;
        const float4 ua = *(const float4*)ar;
        const float4 ub = *(const float4*)(ar + 4);
        FragU aO;
        aO.u[0] = cvt_pk_bf16(ua.x, ua.y);
        aO.u[1] = cvt_pk_bf16(ua.z, ua.w);
        aO.u[2] = cvt_pk_bf16(ub.x, ub.y);
        aO.u[3] = cvt_pk_bf16(ub.z, ub.w);

        const f32x4 y0 = __builtin_amdgcn_mfma_f32_16x16x32_bf16(aO.v, bF[0].v, z, 0, 0, 0);
        const f32x4 y1 = __builtin_amdgcn_mfma_f32_16x16x32_bf16(aO.v, bF[1].v, z, 0, 0, 0);

        // scatter y into outb (reuse; compiler orders RAW/WAR via lgkmcnt)
        #pragma unroll
        for (int r = 0; r < 4; ++r) {
            outb[(gg * 4 + r) * OUT_STRIDE + cc]      = y0[r];
            outb[(gg * 4 + r) * OUT_STRIDE + 16 + cc] = y1[r];
        }

        // gather row-major, + bias, ReLU, coalesced float4 stores
        const int srow = lane >> 2;
        const float* yr0 = outb + srow * OUT_STRIDE + c0;
        float4 v0 = *(const float4*)yr0;
        float4 v1 = *(const float4*)(yr0 + 16);
        v0.x = fmaxf(v0.x + bias0.x, 0.f);
        v0.y = fmaxf(v0.y + bias0.y, 0.f);
        v0.z = fmaxf(v0.z + bias0.z, 0.f);
        v0.w = fmaxf(v0.w + bias0.w, 0.f);
        v1.x = fmaxf(v1.x + bias1.x, 0.f);
        v1.y = fmaxf(v1.y + bias1.y, 0.f);
        v1.z = fmaxf(v1.z + bias1.z, 0.f);
        v1.w = fmaxf(v1.w + bias1.w, 0.f);
        float* yp = Y + (size_t)(rowbase + srow) * 32 + c0;
        *(float4*)yp        = v0;
        *(float4*)(yp + 16) = v1;
    }
}

extern "C" void kernel_launch(void* const* d_in, const int* in_sizes, int n_in,
                              void* d_out, int out_size, void* d_ws, size_t ws_size,
                              hipStream_t stream)
{
    const float* X  = (const float*)d_in[0];
    const float* Wq = (const float*)d_in[1];
    const float* Wk = (const float*)d_in[2];
    const float* Wv = (const float*)d_in[3];
    const float* Wf = (const float*)d_in[4];
    const float* bf = (const float*)d_in[5];
    float* Y = (float*)d_out;

    const int rows = B_ * T_;                         // 1,048,576
    const int rows_per_block = 4 * TILES_PER_WAVE * 16; // 256
    dim3 grid(rows / rows_per_block), block(256);
    hipLaunchKernelGGL(attn_block_mfma, grid, block, 0, stream,
                       X, Wq, Wk, Wv, Wf, bf, Y);
}

// Round 3
// 56.279 us; speedup vs baseline: 2.6758x; 1.3879x over previous
//
#include <hip/hip_runtime.h>
#include <stdint.h>

// Problem constants
#define B_ 131072
#define T_ 8
#define C_ 32
#define H_ 4
#define D_ 8

typedef __attribute__((ext_vector_type(8))) short bf16x8;   // 8 bf16 (4 VGPRs)
typedef __attribute__((ext_vector_type(4))) float f32x4;

union FragU { bf16x8 v; uint32_t u[4]; };

// packed fp32->bf16 (RTNE), 2 values per instruction
__device__ inline uint32_t cvt_pk_bf16(float lo, float hi) {
    uint32_t r;
    asm("v_cvt_pk_bf16_f32 %0, %1, %2" : "=v"(r) : "v"(lo), "v"(hi));
    return r;
}

#define QKV_STRIDE 100   // 96 cols + pad; stride%32 = 4 dwords -> worst 2-way banks (free)
#define TILES_PER_WAVE 4

// One wave handles 16 rows (= 2 causal batches of T=8) per tile iteration.
// LDS is wave-private (q,k,v transpose buffer only): no __syncthreads anywhere.
// Attention output feeds the FF MFMA A-fragment DIRECTLY from registers:
// attention lane (head=gg,row=cc) holds out[row cc, feats gg*8..gg*8+7],
// exactly the A-frag mapping (row=lane&15, k=(lane>>4)*8+j).
__global__ __launch_bounds__(256, 6) void attn_block_mfma(
    const float* __restrict__ X,
    const float* __restrict__ Wq,
    const float* __restrict__ Wk,
    const float* __restrict__ Wv,
    const float* __restrict__ Wf,
    const float* __restrict__ bfb,
    float* __restrict__ Y)
{
    __shared__ float lds[4][QKV_STRIDE * 16];   // 25.6 KB/block -> 6 blocks/CU
    const int wid  = threadIdx.x >> 6;
    const int lane = threadIdx.x & 63;
    const int cc = lane & 15;   // col-in-tile / A-row / attention row
    const int gg = lane >> 4;   // k-group / attention head
    float* qkv = &lds[wid][0];

    const float scale = 0.35355339059327373f;  // 1/sqrt(D), folded into Wq

    // ---------- preamble: weight B-fragments (held in VGPRs) ----------
    // B-frag layout for mfma_f32_16x16x32_bf16: col = lane&15, k = (lane>>4)*8 + jj
    FragU bW[6];   // tiles 0,1 = q(heads0-1,2-3); 2,3 = k; 4,5 = v
    {
        const float* const Ws[3] = { Wq, Wk, Wv };
        #pragma unroll
        for (int tau = 0; tau < 6; ++tau) {
            const float* Wm = Ws[tau >> 1];
            const int col = (tau & 1) * 16 + cc;
            const int head = col >> 3, d = col & 7;
            float f[8];
            #pragma unroll
            for (int jj = 0; jj < 8; ++jj)
                f[jj] = Wm[head * 256 + (gg * 8 + jj) * 8 + d];
            if (tau < 2) {
                #pragma unroll
                for (int jj = 0; jj < 8; ++jj) f[jj] *= scale;
            }
            bW[tau].u[0] = cvt_pk_bf16(f[0], f[1]);
            bW[tau].u[1] = cvt_pk_bf16(f[2], f[3]);
            bW[tau].u[2] = cvt_pk_bf16(f[4], f[5]);
            bW[tau].u[3] = cvt_pk_bf16(f[6], f[7]);
        }
    }
    FragU bF[2];   // FF weight, output col tiles 0,1
    {
        #pragma unroll
        for (int tau = 0; tau < 2; ++tau) {
            const int col = tau * 16 + cc;
            float f[8];
            #pragma unroll
            for (int jj = 0; jj < 8; ++jj)
                f[jj] = Wf[(gg * 8 + jj) * 32 + col];
            bF[tau].u[0] = cvt_pk_bf16(f[0], f[1]);
            bF[tau].u[1] = cvt_pk_bf16(f[2], f[3]);
            bF[tau].u[2] = cvt_pk_bf16(f[4], f[5]);
            bF[tau].u[3] = cvt_pk_bf16(f[6], f[7]);
        }
    }
    // bias for the C-frag-layout store: this lane owns output cols cc and cc+16
    const float bias0 = bfb[cc];
    const float bias1 = bfb[cc + 16];

    const int waveGlobal = blockIdx.x * 4 + wid;
    const f32x4 z = { 0.f, 0.f, 0.f, 0.f };

    // prefetch first X fragment (lane loads row rowbase+cc, floats gg*8..gg*8+7)
    int rowbase = waveGlobal * (16 * TILES_PER_WAVE);
    const float* xp = X + (size_t)(rowbase + cc) * 32 + gg * 8;
    float4 xa = *(const float4*)xp;
    float4 xb = *(const float4*)(xp + 4);

    #pragma unroll 1
    for (int it = 0; it < TILES_PER_WAVE; ++it) {
        rowbase = waveGlobal * (16 * TILES_PER_WAVE) + it * 16;

        // ---- A-frag from X (row = lane&15, k = (lane>>4)*8 + j) ----
        FragU aX;
        aX.u[0] = cvt_pk_bf16(xa.x, xa.y);
        aX.u[1] = cvt_pk_bf16(xa.z, xa.w);
        aX.u[2] = cvt_pk_bf16(xb.x, xb.y);
        aX.u[3] = cvt_pk_bf16(xb.z, xb.w);

        // prefetch next tile's X (clamped; hides HBM latency under attention)
        {
            const int itn = (it + 1 < TILES_PER_WAVE) ? it + 1 : it;
            const float* xpn = X + (size_t)(waveGlobal * (16 * TILES_PER_WAVE) + itn * 16 + cc) * 32 + gg * 8;
            xa = *(const float4*)xpn;
            xb = *(const float4*)(xpn + 4);
        }

        // ---- QKV projection: 6 MFMAs -> 16 rows x 96 cols ----
        f32x4 cq[6];
        #pragma unroll
        for (int tau = 0; tau < 6; ++tau)
            cq[tau] = __builtin_amdgcn_mfma_f32_16x16x32_bf16(aX.v, bW[tau].v, z, 0, 0, 0);

        // scatter C-frags to LDS: row = gg*4 + r, col = tau*16 + cc
        #pragma unroll
        for (int tau = 0; tau < 6; ++tau) {
            #pragma unroll
            for (int r = 0; r < 4; ++r)
                qkv[(gg * 4 + r) * QKV_STRIDE + tau * 16 + cc] = cq[tau][r];
        }

        // ---- attention: lane = (head=gg, row=cc); all 64 lanes busy ----
        const int tpos = cc & 7, bb = cc >> 3;

        const float* qr = qkv + cc * QKV_STRIDE + gg * 8;
        const float4 qa = *(const float4*)qr;
        const float4 qb = *(const float4*)(qr + 4);

        float sc[8];
        #pragma unroll
        for (int s = 0; s < 8; ++s) {
            const float* kr = qkv + (bb * 8 + s) * QKV_STRIDE + 32 + gg * 8;
            const float4 ka = *(const float4*)kr;
            const float4 kb = *(const float4*)(kr + 4);
            float dot =          qa.x * ka.x;
            dot = fmaf(qa.y, ka.y, dot);
            dot = fmaf(qa.z, ka.z, dot);
            dot = fmaf(qa.w, ka.w, dot);
            dot = fmaf(qb.x, kb.x, dot);
            dot = fmaf(qb.y, kb.y, dot);
            dot = fmaf(qb.z, kb.z, dot);
            dot = fmaf(qb.w, kb.w, dot);
            sc[s] = (s <= tpos) ? dot : -1.0e30f;
        }
        float m = sc[0];
        #pragma unroll
        for (int s = 1; s < 8; ++s) m = fmaxf(m, sc[s]);
        float e[8], sum = 0.f;
        #pragma unroll
        for (int s = 0; s < 8; ++s) { e[s] = __expf(sc[s] - m); sum += e[s]; }
        const float winv = 1.0f / sum;

        float4 o03 = { 0.f, 0.f, 0.f, 0.f }, o47 = { 0.f, 0.f, 0.f, 0.f };
        #pragma unroll
        for (int s = 0; s < 8; ++s) {
            const float* vr = qkv + (bb * 8 + s) * QKV_STRIDE + 64 + gg * 8;
            const float4 va = *(const float4*)vr;
            const float4 vb = *(const float4*)(vr + 4);
            o03.x = fmaf(e[s], va.x, o03.x);
            o03.y = fmaf(e[s], va.y, o03.y);
            o03.z = fmaf(e[s], va.z, o03.z);
            o03.w = fmaf(e[s], va.w, o03.w);
            o47.x = fmaf(e[s], vb.x, o47.x);
            o47.y = fmaf(e[s], vb.y, o47.y);
            o47.z = fmaf(e[s], vb.z, o47.z);
            o47.w = fmaf(e[s], vb.w, o47.w);
        }

        // ---- FF A-frag DIRECTLY from attention-output registers ----
        // lane (gg,cc) holds out[row cc, feats gg*8..gg*8+7] == A-frag slice.
        FragU aO;
        aO.u[0] = cvt_pk_bf16(o03.x * winv, o03.y * winv);
        aO.u[1] = cvt_pk_bf16(o03.z * winv, o03.w * winv);
        aO.u[2] = cvt_pk_bf16(o47.x * winv, o47.y * winv);
        aO.u[3] = cvt_pk_bf16(o47.z * winv, o47.w * winv);

        const f32x4 y0 = __builtin_amdgcn_mfma_f32_16x16x32_bf16(aO.v, bF[0].v, z, 0, 0, 0);
        const f32x4 y1 = __builtin_amdgcn_mfma_f32_16x16x32_bf16(aO.v, bF[1].v, z, 0, 0, 0);

        // ---- bias + ReLU in C-frag layout, direct global stores ----
        // lane owns cols cc (y0) and cc+16 (y1), rows gg*4+r. Each store inst
        // covers 4 full 64B segments -> fully coalesced at line granularity.
        #pragma unroll
        for (int r = 0; r < 4; ++r) {
            float* yp = Y + (size_t)(rowbase + gg * 4 + r) * 32;
            yp[cc]      = fmaxf(y0[r] + bias0, 0.f);
            yp[cc + 16] = fmaxf(y1[r] + bias1, 0.f);
        }
    }
}

extern "C" void kernel_launch(void* const* d_in, const int* in_sizes, int n_in,
                              void* d_out, int out_size, void* d_ws, size_t ws_size,
                              hipStream_t stream)
{
    const float* X  = (const float*)d_in[0];
    const float* Wq = (const float*)d_in[1];
    const float* Wk = (const float*)d_in[2];
    const float* Wv = (const float*)d_in[3];
    const float* Wf = (const float*)d_in[4];
    const float* bf = (const float*)d_in[5];
    float* Y = (float*)d_out;

    const int rows = B_ * T_;                           // 1,048,576
    const int rows_per_block = 4 * TILES_PER_WAVE * 16; // 256
    dim3 grid(rows / rows_per_block), block(256);
    hipLaunchKernelGGL(attn_block_mfma, grid, block, 0, stream,
                       X, Wq, Wk, Wv, Wf, bf, Y);
}